// Round 5
// baseline (4078.714 us; speedup 1.0000x reference)
//
#include <hip/hip_runtime.h>
#include <math.h>

typedef unsigned short ushort_t;
typedef short bf16x8 __attribute__((ext_vector_type(8)));   // 8 bf16 = 4 VGPRs (MFMA A/B frag)
typedef float f32x4 __attribute__((ext_vector_type(4)));    // MFMA C/D frag

#define BN_ 4096
#define SN 24
#define TN 24
#define EN 128
#define HN 512
#define GN 1536
#define VN 256
#define BOW_ 1
#define KX 1536   // extended K: [Ahi@Uhi | Alo@Uhi | Ahi@Ulo]
#define HC 1024   // hcat row stride: [hi(512) | lo(512)]

__device__ __forceinline__ float bf2f(ushort_t u) {
    union { unsigned int i; float f; } v; v.i = ((unsigned int)u) << 16; return v.f;
}
__device__ __forceinline__ ushort_t f2bf(float f) {  // round-to-nearest-even
    union { float f; unsigned int i; } v; v.f = f;
    unsigned int r = (v.i + 0x7FFFu + ((v.i >> 16) & 1u)) >> 16;
    return (ushort_t)r;
}

// async global->LDS, 16B per lane. LDS dest = wave-uniform base + lane*16 (HW).
__device__ __forceinline__ void gload16(const void* g, void* l) {
    __builtin_amdgcn_global_load_lds(
        (const __attribute__((address_space(1))) unsigned int*)g,
        (__attribute__((address_space(3))) unsigned int*)l, 16, 0, 0);
}

template<int N> __device__ __forceinline__ void waitcnt_vm() {
    if constexpr (N == 0)       asm volatile("s_waitcnt vmcnt(0)" ::: "memory");
    else if constexpr (N == 4)  asm volatile("s_waitcnt vmcnt(4)" ::: "memory");
    else if constexpr (N == 5)  asm volatile("s_waitcnt vmcnt(5)" ::: "memory");
    else if constexpr (N == 8)  asm volatile("s_waitcnt vmcnt(8)" ::: "memory");
    else if constexpr (N == 10) asm volatile("s_waitcnt vmcnt(10)" ::: "memory");
    else static_assert(N == 0, "unsupported vmcnt");
}
__device__ __forceinline__ void barrier_() { asm volatile("s_barrier" ::: "memory"); }

__global__ void zero_kernel(float4* __restrict__ p, int n16) {
    int i = blockIdx.x * blockDim.x + threadIdx.x;
    if (i < n16) p[i] = make_float4(0.f, 0.f, 0.f, 0.f);
}

// P[mat] = emb @ W + b_input  for (Wf,src), (Wb,src), (Wd,tgt). One block per (mat,row).
__global__ void precomp_P(const float* __restrict__ src_emb, const float* __restrict__ tgt_emb,
                          const float* __restrict__ Wf, const float* __restrict__ bf,
                          const float* __restrict__ Wb, const float* __restrict__ bb,
                          const float* __restrict__ Wd, const float* __restrict__ bd,
                          float* __restrict__ Pf, float* __restrict__ Pb, float* __restrict__ Pd) {
    int mat = blockIdx.x / VN;
    int row = blockIdx.x % VN;
    const float* emb = (mat == 2) ? tgt_emb : src_emb;
    const float* W   = (mat == 0) ? Wf : (mat == 1) ? Wb : Wd;
    const float* bia = (mat == 0) ? bf : (mat == 1) ? bb : bd;
    float* P         = (mat == 0) ? Pf : (mat == 1) ? Pb : Pd;
    __shared__ float e[EN];
    for (int i = threadIdx.x; i < EN; i += blockDim.x) e[i] = emb[row * EN + i];
    __syncthreads();
    for (int c = threadIdx.x; c < GN; c += blockDim.x) {
        float s = bia[c];
#pragma unroll 8
        for (int k = 0; k < EN; k++) s += e[k] * W[k * GN + c];
        P[row * GN + c] = s;
    }
}

// B' tables for the recurrent GEMM: Bt[col][k], k in [0,1536):
//   k<512: bf16hi(U[k][col]); k<1024: bf16hi(U[k-512][col]); k>=1024: bf16lo(U[k-1024][col])
__global__ void precomp_Bt(const float* __restrict__ Uf, const float* __restrict__ Ub,
                           const float* __restrict__ Ud,
                           ushort_t* __restrict__ BtF, ushort_t* __restrict__ BtB,
                           ushort_t* __restrict__ BtD) {
    int mat = blockIdx.x / GN;
    int col = blockIdx.x % GN;
    const float* U = (mat == 0) ? Uf : (mat == 1) ? Ub : Ud;
    ushort_t* Bt   = (mat == 0) ? BtF : (mat == 1) ? BtB : BtD;
    for (int k = threadIdx.x; k < KX; k += blockDim.x) {
        int ke = (k < HN) ? k : (k < 2 * HN) ? (k - HN) : (k - 2 * HN);
        float u = U[ke * GN + col];
        ushort_t hi = f2bf(u);
        Bt[(size_t)col * KX + k] = (k >= 2 * HN) ? f2bf(u - bf2f(hi)) : hi;
    }
}

__global__ void precomp_Wot(const float* __restrict__ Wo, ushort_t* __restrict__ Wot) {
    int col = blockIdx.x;  // 0..255
    for (int k = threadIdx.x; k < KX; k += blockDim.x) {
        int ke = (k < HN) ? k : (k < 2 * HN) ? (k - HN) : (k - 2 * HN);
        float u = Wo[ke * VN + col];
        ushort_t hi = f2bf(u);
        Wot[(size_t)col * KX + k] = (k >= 2 * HN) ? f2bf(u - bf2f(hi)) : hi;
    }
}

// decoder init state = hf_final + hb_final, stored as hi/lo bf16 pair
__global__ void dec_init(const ushort_t* __restrict__ hf, const ushort_t* __restrict__ hb,
                         ushort_t* __restrict__ hd) {
    int i = blockIdx.x * blockDim.x + threadIdx.x;
    if (i >= BN_ * HN) return;
    int row = i >> 9, col = i & (HN - 1);
    float h = bf2f(hf[(size_t)row * HC + col]) + bf2f(hf[(size_t)row * HC + HN + col])
            + bf2f(hb[(size_t)row * HC + col]) + bf2f(hb[(size_t)row * HC + HN + col]);
    ushort_t hi = f2bf(h);
    hd[(size_t)row * HC + col] = hi;
    hd[(size_t)row * HC + HN + col] = f2bf(h - bf2f(hi));
}

// One GRU step via bf16 MFMA split GEMM.
// M-tile 64 rows, 4 waves each owning 64 rows x 16 cols x 3 gates. K: 48 chunks of 32.
// XCD-aware remap: my_y = bx&7 (same 64-col B-slice per XCD -> Bt L2-resident),
// my_m = (bx>>3) + 8*by. Grid x MUST be 64 so linear_id%8 == bx&7.
// Staging: global_load_lds(16B), both-sides XOR swizzle (r4-verified, 0 conflicts).
// PD = pipeline depth (2 = double buffer, 3 = triple buffer w/ 2-chunk prefetch).
// mode: 0 enc-fwd, 1 enc-bwd, 2 dec. blockIdx.z picks param set A/B.
template<int PD>
__global__ __launch_bounds__(256, 4) void gru_step(
    const ushort_t* __restrict__ hA_in, ushort_t* __restrict__ hA_out,
    const ushort_t* __restrict__ BtA, const float* __restrict__ brA,
    const float* __restrict__ PA, int modeA,
    const ushort_t* __restrict__ hB_in, ushort_t* __restrict__ hB_out,
    const ushort_t* __restrict__ BtB, const float* __restrict__ brB,
    const float* __restrict__ PB, int modeB,
    const int* __restrict__ tok, int t) {
    const ushort_t* hin; ushort_t* hout; const ushort_t* Bt; const float* brec; const float* P; int mode;
    if (blockIdx.z == 0) { hin = hA_in; hout = hA_out; Bt = BtA; brec = brA; P = PA; mode = modeA; }
    else                 { hin = hB_in; hout = hB_out; Bt = BtB; brec = brB; P = PB; mode = modeB; }

    const int bx = blockIdx.x, by = blockIdx.y;
    const int bm = (((bx >> 3) + 8 * by) << 6);   // row tile (64)
    const int bj = ((bx & 7) << 6);               // h-col tile (64) == XCD id
    const int tid = threadIdx.x;
    const int lane = tid & 63;
    const int w = tid >> 6;                       // wave = col sub-tile (16 cols)

    __shared__ __align__(16) short Asm[PD][64 * 32];
    __shared__ __align__(16) short Bsm[PD][192 * 32];

    f32x4 acc[3][4];
#pragma unroll
    for (int g = 0; g < 3; g++)
#pragma unroll
        for (int i = 0; i < 4; i++) acc[g][i] = (f32x4){0.f, 0.f, 0.f, 0.f};

    const int fl = lane & 15;
    const int fke = (((lane >> 4) ^ ((lane >> 1) & 3)) * 8);    // swizzled read slot
    const int lr = lane >> 2;                                   // staging row in 16-row group
    const int lk = (((lane & 3) ^ ((lane >> 3) & 3)) * 8);      // swizzled global slot

    auto stage = [&](int buf, int kc) {
        const int gk = kc * 32;
        const int agk = (gk >= 2 * HN) ? (gk - 2 * HN) : gk;    // A reuses hi for term 3
        const int r0a = w * 16;
        gload16(hin + (size_t)(bm + r0a + lr) * HC + agk + lk, &Asm[buf][r0a * 32]);
#pragma unroll
        for (int s = 0; s < 3; ++s) {
            const int r0 = w * 48 + s * 16;
            const int r = r0 + lr;
            gload16(Bt + (size_t)((r >> 6) * HN + bj + (r & 63)) * KX + gk + lk,
                    &Bsm[buf][r0 * 32]);
        }
    };

    stage(0, 0);
    if constexpr (PD == 3) stage(1, 1);

    int cur = 0;
    for (int kc = 0; kc < 48; ++kc) {
        if constexpr (PD == 2) {
            if (kc < 47) { stage(cur ^ 1, kc + 1); waitcnt_vm<4>(); }
            else         { waitcnt_vm<0>(); }
        } else {
            if (kc < 46) {
                int pre = cur + 2; if (pre >= 3) pre -= 3;
                stage(pre, kc + 2); waitcnt_vm<8>();
            } else if (kc == 46) { waitcnt_vm<4>(); }
            else                 { waitcnt_vm<0>(); }
        }
        barrier_();                       // buf[cur] ready for all waves
        const short* Ab = Asm[cur];
        const short* Bb = Bsm[cur];
        bf16x8 af[4];
#pragma unroll
        for (int i = 0; i < 4; i++)
            af[i] = *(const bf16x8*)&Ab[(i * 16 + fl) * 32 + fke];
#pragma unroll
        for (int g = 0; g < 3; g++) {
            bf16x8 bfr = *(const bf16x8*)&Bb[(g * 64 + w * 16 + fl) * 32 + fke];
#pragma unroll
            for (int i = 0; i < 4; i++)
                acc[g][i] = __builtin_amdgcn_mfma_f32_16x16x32_bf16(af[i], bfr, acc[g][i], 0, 0, 0);
        }
        barrier_();                       // all reads done -> buffer may be overwritten
        if constexpr (PD == 2) cur ^= 1;
        else { cur = (cur == 2) ? 0 : cur + 1; }
    }

    const int fq = lane >> 4;
#pragma unroll
    for (int i = 0; i < 4; i++) {
#pragma unroll
        for (int q = 0; q < 4; q++) {
            const int row = bm + i * 16 + fq * 4 + q;
            int idx;
            if (mode == 2) idx = (t == 0) ? BOW_ : tok[row * TN + (t - 1)];
            else           idx = tok[row * SN + ((mode == 0) ? t : (SN - 1 - t))];
            const float* Pr = P + (size_t)idx * GN;
            const int col = bj + w * 16 + fl;
            float rz = acc[0][i][q] + brec[col];
            float rr = acc[1][i][q] + brec[HN + col];
            float rh = acc[2][i][q] + brec[2 * HN + col];
            float z = 1.f / (1.f + expf(-(Pr[col] + rz)));
            float r = 1.f / (1.f + expf(-(Pr[HN + col] + rr)));
            float hh = tanhf(Pr[2 * HN + col] + r * rh);
            float ho = bf2f(hin[(size_t)row * HC + col]) + bf2f(hin[(size_t)row * HC + HN + col]);
            float hnew = z * ho + (1.f - z) * hh;
            ushort_t hib = f2bf(hnew);
            hout[(size_t)row * HC + col] = hib;
            hout[(size_t)row * HC + HN + col] = f2bf(hnew - bf2f(hib));
        }
    }
}

// logits[:, t, :] = hd @ Wo + bo via split GEMM. M=4096 (64-row tiles), N=256 full,
// K=1536(split). 4 waves of 64x64; A read once per block; PD=3 prefetch.
__global__ __launch_bounds__(256) void logits_mfma(
    const ushort_t* __restrict__ hin, const ushort_t* __restrict__ Wot,
    const float* __restrict__ bo, float* __restrict__ out, int t) {
    const int bm = blockIdx.x * 64;
    const int tid = threadIdx.x;
    const int lane = tid & 63;
    const int w = tid >> 6;   // 64-col sub-tile

    __shared__ __align__(16) short Asm[3][64 * 32];
    __shared__ __align__(16) short Bsm[3][256 * 32];

    f32x4 acc[4][4];
#pragma unroll
    for (int i = 0; i < 4; i++)
#pragma unroll
        for (int n = 0; n < 4; n++) acc[i][n] = (f32x4){0.f, 0.f, 0.f, 0.f};

    const int fl = lane & 15;
    const int fke = (((lane >> 4) ^ ((lane >> 1) & 3)) * 8);
    const int lr = lane >> 2;
    const int lk = (((lane & 3) ^ ((lane >> 3) & 3)) * 8);

    auto stage = [&](int buf, int kc) {
        const int gk = kc * 32;
        const int agk = (gk >= 2 * HN) ? (gk - 2 * HN) : gk;
        const int r0a = w * 16;
        gload16(hin + (size_t)(bm + r0a + lr) * HC + agk + lk, &Asm[buf][r0a * 32]);
#pragma unroll
        for (int s = 0; s < 4; ++s) {
            const int r0 = w * 64 + s * 16;
            gload16(Wot + (size_t)(r0 + lr) * KX + gk + lk, &Bsm[buf][r0 * 32]);
        }
    };

    stage(0, 0);
    stage(1, 1);

    int cur = 0;
    for (int kc = 0; kc < 48; ++kc) {
        if (kc < 46) {
            int pre = cur + 2; if (pre >= 3) pre -= 3;
            stage(pre, kc + 2); waitcnt_vm<10>();
        } else if (kc == 46) { waitcnt_vm<5>(); }
        else                 { waitcnt_vm<0>(); }
        barrier_();
        const short* Ab = Asm[cur];
        const short* Bb = Bsm[cur];
        bf16x8 af[4];
#pragma unroll
        for (int i = 0; i < 4; i++)
            af[i] = *(const bf16x8*)&Ab[(i * 16 + fl) * 32 + fke];
#pragma unroll
        for (int n = 0; n < 4; n++) {
            bf16x8 bfr = *(const bf16x8*)&Bb[(w * 64 + n * 16 + fl) * 32 + fke];
#pragma unroll
            for (int i = 0; i < 4; i++)
                acc[i][n] = __builtin_amdgcn_mfma_f32_16x16x32_bf16(af[i], bfr, acc[i][n], 0, 0, 0);
        }
        barrier_();
        cur = (cur == 2) ? 0 : cur + 1;
    }

    const int fq = lane >> 4;
#pragma unroll
    for (int i = 0; i < 4; i++) {
#pragma unroll
        for (int q = 0; q < 4; q++) {
            const int row = bm + i * 16 + fq * 4 + q;
#pragma unroll
            for (int n = 0; n < 4; n++) {
                const int col = w * 64 + n * 16 + fl;
                out[(size_t)row * (TN * VN) + t * VN + col] = acc[i][n][q] + bo[col];
            }
        }
    }
}

extern "C" void kernel_launch(void* const* d_in, const int* in_sizes, int n_in,
                              void* d_out, int out_size, void* d_ws, size_t ws_size,
                              hipStream_t stream) {
    const int* source    = (const int*)d_in[0];
    const int* targets   = (const int*)d_in[1];
    const float* src_emb = (const float*)d_in[2];
    const float* tgt_emb = (const float*)d_in[3];
    const float* Wf = (const float*)d_in[4];
    const float* Uf = (const float*)d_in[5];
    const float* bf = (const float*)d_in[6];
    const float* Wb = (const float*)d_in[7];
    const float* Ub = (const float*)d_in[8];
    const float* bb = (const float*)d_in[9];
    const float* Wd = (const float*)d_in[10];
    const float* Ud = (const float*)d_in[11];
    const float* bd = (const float*)d_in[12];
    const float* Wo = (const float*)d_in[13];
    const float* bo = (const float*)d_in[14];
    float* out = (float*)d_out;

    char* ws = (char*)d_ws;
    ushort_t* BtF = (ushort_t*)(ws);                              // 1536*1536*2 = 4718592
    ushort_t* BtB = (ushort_t*)(ws + 4718592);
    ushort_t* BtD = (ushort_t*)(ws + 2 * 4718592);
    ushort_t* Wot = (ushort_t*)(ws + 3 * 4718592);                // 256*1536*2 = 786432
    float*    Pf  = (float*)   (ws + 3 * 4718592 + 786432);       // 3*256*1536*4 = 4718592
    float*    Pb  = Pf + VN * GN;
    float*    Pd  = Pb + VN * GN;
    char* hbase = ws + 4 * 4718592 + 786432;                      // 4 x 4096*1024*2 = 4 x 8388608
    ushort_t* hf0 = (ushort_t*)(hbase);
    ushort_t* hf1 = (ushort_t*)(hbase + 8388608);
    ushort_t* hb0 = (ushort_t*)(hbase + 2 * 8388608);
    ushort_t* hb1 = (ushort_t*)(hbase + 3 * 8388608);

    // zero all 4 h buffers (33.5 MB)
    zero_kernel<<<8192, 256, 0, stream>>>((float4*)hbase, 2097152);
    precomp_P<<<3 * VN, 256, 0, stream>>>(src_emb, tgt_emb, Wf, bf, Wb, bb, Wd, bd, Pf, Pb, Pd);
    precomp_Bt<<<3 * GN, 256, 0, stream>>>(Uf, Ub, Ud, BtF, BtB, BtD);
    precomp_Wot<<<VN, 256, 0, stream>>>(Wo, Wot);

    // encoder: both directions per launch; 64-row tiles, 1024 blocks = 4/CU, PD=2
    for (int t = 0; t < SN; t++) {
        const ushort_t* hfi = (t & 1) ? hf1 : hf0; ushort_t* hfo = (t & 1) ? hf0 : hf1;
        const ushort_t* hbi = (t & 1) ? hb1 : hb0; ushort_t* hbo = (t & 1) ? hb0 : hb1;
        gru_step<2><<<dim3(64, 8, 2), 256, 0, stream>>>(
            hfi, hfo, BtF, bf + GN, Pf, 0,
            hbi, hbo, BtB, bb + GN, Pb, 1,
            source, t);
    }
    // decoder init state into hb1 (free after encoder; finals are in hf0/hb0)
    dec_init<<<(BN_ * HN + 255) / 256, 256, 0, stream>>>(hf0, hb0, hb1);

    // decoder + per-step logits (ping-pong hb1 <-> hf1); 512 blocks = 2/CU, PD=3
    for (int t = 0; t < TN; t++) {
        const ushort_t* hdi = (t & 1) ? hf1 : hb1; ushort_t* hdo = (t & 1) ? hb1 : hf1;
        gru_step<3><<<dim3(64, 8, 1), 256, 0, stream>>>(
            hdi, hdo, BtD, bd + GN, Pd, 2,
            nullptr, nullptr, nullptr, nullptr, nullptr, 0,
            targets, t);
        logits_mfma<<<64, 256, 0, stream>>>(hdo, Wot, bo, out, t);
    }
}